// Round 1
// 159.212 us; speedup vs baseline: 1.0516x; 1.0516x over previous
//
#include <hip/hip_runtime.h>
#include <hip/hip_bf16.h>

// Problem constants
#define BB    8
#define NBB   1024
#define KK    9
#define CC    32
#define CMM   128
#define NTOT  (BB*NBB)        // 8192
#define MM    (NBB*KK)        // 9216 per batch
#define MS    16              // K-split ways
#define MR    (MM/MS)         // 576 m per split
#define NEG   0.01f
#define EPS   1e-5f
#define L2C   (-2.8853900817779268f)   /* -2*log2(e) */

// Workspace layout (floats)
#define OFF_CWT   0
#define SZ_CWT    (BB*CC*MM/2)            // bf16 as float-slots: 1179648
#define OFF_CFX   (OFF_CWT + SZ_CWT)
#define OFF_CFY   (OFF_CFX + BB*MM)
#define OFF_CF0   (OFF_CFY + BB*MM)
#define OFF_PART  (OFF_CF0 + BB*MM)
#define SZ_ONE    (NTOT*CC)               // 262144
#define SZ_PART   (MS*SZ_ONE)
// aliases into dead partial slots (consumed by k_leaky_stats before reuse)
#define OFF_X0    (OFF_PART)              // slot 0 (same-thread RAW in k_leaky)
#define OFF_X     (OFF_PART + SZ_ONE)     // slot 1
#define OFF_H0    (OFF_PART + 2*SZ_ONE)   // slots 2..5
#define OFF_ST    (OFF_PART + SZ_PART)    // stats: s1[64] then s2[256]

typedef __attribute__((ext_vector_type(8))) short short8;
typedef __attribute__((ext_vector_type(4))) float f32x4;
typedef __attribute__((ext_vector_type(2))) float f32x2;

static __device__ __forceinline__ unsigned short f2bf_rne(float f) {
    __hip_bfloat16 h = __float2bfloat16(f);
    return *reinterpret_cast<unsigned short*>(&h);
}

// ---------------------------------------------------------------------------
// k_convw (MFMA) + folded prep:
//   prep: per-m Gaussian coefs cfx/cfy/cf0; block 0 zeroes stats.
//   convw: cwT[b][c][m] bf16, m = nloc*9+k,
//     conv_w[n][k][c] = sum_cp w[n][cp] * kw[k][cp][c]
//   kw is staged in LDS as bf16 transposed [k][c][cp] so each A-frag is ONE
//   ds_read_b128 (was 144 scalar global loads + cvts per lane at 1 wave/SIMD).
// grid = 128 (8 b x 16 nblk of 64 n); wave = 16 n.
// ---------------------------------------------------------------------------
__global__ __launch_bounds__(256) void k_convw(const float* __restrict__ pos,
                                               const float* __restrict__ kpos,
                                               const float* __restrict__ w,
                                               const float* __restrict__ kw,
                                               float* __restrict__ cfx,
                                               float* __restrict__ cfy,
                                               float* __restrict__ cf0,
                                               float* __restrict__ stats,
                                               short* __restrict__ cwT) {
    __shared__ unsigned short tile[4*32*144];   // 36 KB, per-wave tiles
    __shared__ unsigned short kwl[KK*CC*CC];    // 18 KB, kwT bf16 [k][c][cp]
    int t = threadIdx.x;
    int l = t & 63, wv = t >> 6;
    int lane15 = l & 15, quad = l >> 4;
    int blk = blockIdx.x;
    int b = blk >> 4, nbl = blk & 15;
    int n = b*NBB + nbl*64 + wv*16 + lane15;

    // ---- folded k_prep: 73728 items over 32768 threads (<=3 each) ----
    if (blk == 0 && t < 320) stats[t] = 0.f;
    #pragma unroll
    for (int rep = 0; rep < 3; ++rep) {
        int gid = blk*256 + t + rep*32768;
        if (gid < BB*MM) {
            int bb = gid / MM;
            int m = gid - bb*MM;
            int np = m / 9, k9 = m - np*9;
            float qx = pos[((size_t)(bb*NBB + np))*2 + 0] + kpos[k9*2 + 0];
            float qy = pos[((size_t)(bb*NBB + np))*2 + 1] + kpos[k9*2 + 1];
            cfx[gid] = -2.f*L2C*qx;
            cfy[gid] = -2.f*L2C*qy;
            cf0[gid] = L2C*(qx*qx + qy*qy);
        }
    }

    // ---- stage kw -> LDS bf16 transposed [k][c][cp] ----
    // kw[k][cp][c] flat = (k*32+cp)*32 + c ; vector-load 4 consecutive c
    for (int u = t; u < KK*CC*CC/4; u += 256) {
        int flat = u*4;               // (kk*32+cp)*32 + c0
        int row  = flat >> 5;         // kk*32+cp
        int c0   = flat & 31;
        int kk = row >> 5, cp = row & 31;
        f32x4 v = *(const f32x4*)&kw[flat];
        kwl[(kk*CC + c0+0)*CC + cp] = f2bf_rne(v.x);
        kwl[(kk*CC + c0+1)*CC + cp] = f2bf_rne(v.y);
        kwl[(kk*CC + c0+2)*CC + cp] = f2bf_rne(v.z);
        kwl[(kk*CC + c0+3)*CC + cp] = f2bf_rne(v.w);
    }

    // B-frag: w[n][quad*8 .. +7] -> bf16
    f32x4 w0 = *(const f32x4*)&w[(size_t)n*CC + quad*8];
    f32x4 w1 = *(const f32x4*)&w[(size_t)n*CC + quad*8 + 4];
    union { unsigned short us[8]; short8 s; } bfr;
    bfr.us[0] = f2bf_rne(w0.x); bfr.us[1] = f2bf_rne(w0.y);
    bfr.us[2] = f2bf_rne(w0.z); bfr.us[3] = f2bf_rne(w0.w);
    bfr.us[4] = f2bf_rne(w1.x); bfr.us[5] = f2bf_rne(w1.y);
    bfr.us[6] = f2bf_rne(w1.z); bfr.us[7] = f2bf_rne(w1.w);

    __syncthreads();   // kwl ready

    f32x4 acc[KK][2];
    #pragma unroll
    for (int kk = 0; kk < KK; ++kk) {
        #pragma unroll
        for (int ct = 0; ct < 2; ++ct) {
            int c = ct*16 + lane15;
            // A-frag: kwT[kk][c][quad*8 .. +7] — one b128 LDS read,
            // 64 lanes x 16B contiguous, conflict-free
            short8 afr = *(const short8*)&kwl[(kk*CC + c)*CC + quad*8];
            acc[kk][ct] = __builtin_amdgcn_mfma_f32_16x16x32_bf16(
                afr, bfr.s, (f32x4)0.f, 0, 0, 0);
        }
    }
    // D: col(n)=lane15, row(c)=quad*4+reg. Stash to per-wave LDS tile [c][nloc*9+k]
    unsigned short* tw = tile + wv*4608;
    #pragma unroll
    for (int kk = 0; kk < KK; ++kk)
        #pragma unroll
        for (int ct = 0; ct < 2; ++ct)
            #pragma unroll
            for (int reg = 0; reg < 4; ++reg) {
                int c = ct*16 + quad*4 + reg;
                tw[c*144 + lane15*9 + kk] = f2bf_rne(acc[kk][ct][reg]);
            }
    __syncthreads();
    // coalesced writeout: 9 insts x 64 lanes covering 32 c x 144 m (per wave)
    short* dst = cwT + (size_t)b*CC*MM + (size_t)(nbl*64 + wv*16)*9;
    #pragma unroll
    for (int it = 0; it < 9; ++it) {
        int u = it*64 + l;
        int c = u / 18, seg = u - c*18;
        short8 v = *(const short8*)&tw[c*144 + seg*8];
        *(short8*)&dst[(size_t)c*MM + seg*8] = v;
    }
}

// ---------------------------------------------------------------------------
// k_sample (dominant, MFMA): part[ks][n][c] = sum_{m} exp2(E) * conv_w[m][c]
// M=c, N=n, K=m. A from cwT global (L1-shared), B = e in registers. NO LDS.
// grid = 8 b x 8 nblk(128 n) x 16 ksplit = 1024 blocks; wave = 2 n-tiles.
// ---------------------------------------------------------------------------
__global__ __launch_bounds__(256) void k_sample(const float* __restrict__ pos,
                                                const float* __restrict__ cfx,
                                                const float* __restrict__ cfy,
                                                const float* __restrict__ cf0,
                                                const short* __restrict__ cwT,
                                                float* __restrict__ part) {
    int t = threadIdx.x;
    int l = t & 63, w = t >> 6;
    int blk = blockIdx.x;
    int ks = blk & 15, nb = (blk >> 4) & 7, b = blk >> 7;
    int lane15 = l & 15, quad = l >> 4;
    int nbase = b*NBB + nb*128 + w*32;

    float px[2], py[2], cn[2];
    #pragma unroll
    for (int nt = 0; nt < 2; ++nt) {
        int n = nbase + nt*16 + lane15;
        float x = pos[(size_t)n*2], y = pos[(size_t)n*2 + 1];
        px[nt] = x; py[nt] = y; cn[nt] = L2C*(x*x + y*y);
    }
    f32x4 acc[2][2];
    #pragma unroll
    for (int nt = 0; nt < 2; ++nt) { acc[nt][0] = (f32x4)0.f; acc[nt][1] = (f32x4)0.f; }

    const float* bx = cfx + (size_t)b*MM;
    const float* by = cfy + (size_t)b*MM;
    const float* b0 = cf0 + (size_t)b*MM;
    const short* ca0 = cwT + (size_t)b*CC*MM + (size_t)lane15*MM;
    const short* ca1 = ca0 + (size_t)16*MM;

    int m0 = ks*MR + quad*8;
    #pragma unroll 2
    for (int kk = 0; kk < MR/32; ++kk, m0 += 32) {
        short8 a0 = *(const short8*)&ca0[m0];
        short8 a1 = *(const short8*)&ca1[m0];
        f32x4 vx0 = *(const f32x4*)&bx[m0];
        f32x4 vx1 = *(const f32x4*)&bx[m0 + 4];
        f32x4 vy0 = *(const f32x4*)&by[m0];
        f32x4 vy1 = *(const f32x4*)&by[m0 + 4];
        f32x4 v00 = *(const f32x4*)&b0[m0];
        f32x4 v01 = *(const f32x4*)&b0[m0 + 4];
        #pragma unroll
        for (int nt = 0; nt < 2; ++nt) {
            f32x2 Xv = {px[nt], px[nt]};
            f32x2 Yv = {py[nt], py[nt]};
            f32x2 Cv = {cn[nt], cn[nt]};
            // E pairs via packed fma (v_pk_fma_f32)
            f32x2 t0 = (f32x2){v00.x, v00.y} + Cv;
            t0 = (f32x2){vy0.x, vy0.y}*Yv + t0;
            t0 = (f32x2){vx0.x, vx0.y}*Xv + t0;
            f32x2 t1 = (f32x2){v00.z, v00.w} + Cv;
            t1 = (f32x2){vy0.z, vy0.w}*Yv + t1;
            t1 = (f32x2){vx0.z, vx0.w}*Xv + t1;
            f32x2 t2 = (f32x2){v01.x, v01.y} + Cv;
            t2 = (f32x2){vy1.x, vy1.y}*Yv + t2;
            t2 = (f32x2){vx1.x, vx1.y}*Xv + t2;
            f32x2 t3 = (f32x2){v01.z, v01.w} + Cv;
            t3 = (f32x2){vy1.z, vy1.w}*Yv + t3;
            t3 = (f32x2){vx1.z, vx1.w}*Xv + t3;
            float e0 = __builtin_amdgcn_exp2f(t0.x);
            float e1 = __builtin_amdgcn_exp2f(t0.y);
            float e2 = __builtin_amdgcn_exp2f(t1.x);
            float e3 = __builtin_amdgcn_exp2f(t1.y);
            float e4 = __builtin_amdgcn_exp2f(t2.x);
            float e5 = __builtin_amdgcn_exp2f(t2.y);
            float e6 = __builtin_amdgcn_exp2f(t3.x);
            float e7 = __builtin_amdgcn_exp2f(t3.y);
            union { unsigned int u[4]; short8 s; } bf;
            bf.u[0] = (__float_as_uint(e0) >> 16) | (__float_as_uint(e1) & 0xffff0000u);
            bf.u[1] = (__float_as_uint(e2) >> 16) | (__float_as_uint(e3) & 0xffff0000u);
            bf.u[2] = (__float_as_uint(e4) >> 16) | (__float_as_uint(e5) & 0xffff0000u);
            bf.u[3] = (__float_as_uint(e6) >> 16) | (__float_as_uint(e7) & 0xffff0000u);
            acc[nt][0] = __builtin_amdgcn_mfma_f32_16x16x32_bf16(a0, bf.s, acc[nt][0], 0, 0, 0);
            acc[nt][1] = __builtin_amdgcn_mfma_f32_16x16x32_bf16(a1, bf.s, acc[nt][1], 0, 0, 0);
        }
    }
    // D: col(n)=lane15, row(c)=quad*4+reg
    #pragma unroll
    for (int nt = 0; nt < 2; ++nt) {
        int n = nbase + nt*16 + lane15;
        #pragma unroll
        for (int ct = 0; ct < 2; ++ct) {
            int c = ct*16 + quad*4;
            *(f32x4*)&part[((size_t)ks*NTOT + n)*CC + c] = acc[nt][ct];
        }
    }
}

// ---------------------------------------------------------------------------
// k_leaky_stats: x0 = leaky(sum of 16 partials); accumulate bn1 sum/sumsq
// ---------------------------------------------------------------------------
__global__ __launch_bounds__(256) void k_leaky_stats(const float* __restrict__ part,
                                                     float* __restrict__ x0,
                                                     float* __restrict__ s1) {
    __shared__ float ss[32], sq[32];
    int t = threadIdx.x;
    if (t < 32) { ss[t] = 0.f; sq[t] = 0.f; }
    __syncthreads();
    float lsum = 0.f, lsq = 0.f;
    int base = blockIdx.x * 1024;
    for (int j = 0; j < 4; ++j) {
        int idx = base + j*256 + t;
        float v = 0.f;
        #pragma unroll
        for (int s = 0; s < MS; ++s) v += part[(size_t)s*SZ_ONE + idx];
        v = v >= 0.f ? v : NEG*v;
        x0[idx] = v;   // aliases partial slot 0: same-thread read-then-write
        lsum += v; lsq = fmaf(v, v, lsq);
    }
    atomicAdd(&ss[t & 31], lsum);
    atomicAdd(&sq[t & 31], lsq);
    __syncthreads();
    if (t < 32) { atomicAdd(&s1[t], ss[t]); atomicAdd(&s1[32+t], sq[t]); }
}

// ---------------------------------------------------------------------------
// k_mlp1: x = bn1(x0) + weights; h0 = leaky(x @ W1 + b1); fused bn2 stats.
// grid = 256: block = 64 n x 64 j (j-half). W1 rows via wave-uniform s_load.
// Stats: LDS transpose [j][n] -> 4-lane partial sums -> global atomics.
// ---------------------------------------------------------------------------
__global__ __launch_bounds__(256) void k_mlp1(const float* __restrict__ x0,
                                              const float* __restrict__ wts,
                                              const float* __restrict__ gma,
                                              const float* __restrict__ bta,
                                              const float* __restrict__ W1,
                                              const float* __restrict__ b1,
                                              const float* __restrict__ s1,
                                              float* __restrict__ x,
                                              float* __restrict__ h0,
                                              float* __restrict__ s2) {
    __shared__ float tile[64*68];   // [j_local][n] padded
    int t = threadIdx.x;
    int l = t & 63, w = t >> 6;
    int blk = blockIdx.x;
    int nb = blk >> 1, jh = blk & 1;
    int n = nb*64 + l;
    int j0 = jh*64 + w*16;

    float xv[32];
    #pragma unroll
    for (int c = 0; c < 32; ++c) {
        float mu  = s1[c] * (1.f/NTOT);
        float var = s1[32+c]*(1.f/NTOT) - mu*mu;
        float a   = gma[c] * rsqrtf(var + EPS);
        float v   = x0[(size_t)n*CC + c];
        xv[c] = a*(v - mu) + bta[c] + wts[(size_t)n*CC + c];
    }
    if (jh == 0 && w == 0) {
        #pragma unroll
        for (int c = 0; c < 32; c += 4)
            *(float4*)&x[(size_t)n*CC + c] = make_float4(xv[c], xv[c+1], xv[c+2], xv[c+3]);
    }
    float acc[16];
    #pragma unroll
    for (int jj = 0; jj < 16; ++jj) acc[jj] = b1[j0 + jj];
    #pragma unroll 4
    for (int c = 0; c < 32; ++c) {
        float xc = xv[c];
        const float* w1r = W1 + c*CMM + j0;   // wave-uniform -> s_load
        #pragma unroll
        for (int jj = 0; jj < 16; ++jj)
            acc[jj] = fmaf(xc, w1r[jj], acc[jj]);
    }
    float* hd = h0 + (size_t)n*CMM + j0;
    #pragma unroll
    for (int jj = 0; jj < 16; ++jj) {
        acc[jj] = acc[jj] >= 0.f ? acc[jj] : NEG*acc[jj];
        tile[(w*16 + jj)*68 + l] = acc[jj];
    }
    #pragma unroll
    for (int jj = 0; jj < 16; jj += 4)
        *(float4*)&hd[jj] = make_float4(acc[jj], acc[jj+1], acc[jj+2], acc[jj+3]);
    __syncthreads();
    // stats: thread -> (j_local = t>>2, grp = t&3), sum 16 n's each
    int jl = t >> 2, grp = t & 3;
    float lsum = 0.f, lsq = 0.f;
    #pragma unroll
    for (int q = 0; q < 4; ++q) {
        f32x4 v = *(const f32x4*)&tile[jl*68 + grp*16 + q*4];
        lsum += v.x + v.y + v.z + v.w;
        lsq = fmaf(v.x, v.x, fmaf(v.y, v.y, fmaf(v.z, v.z, fmaf(v.w, v.w, lsq))));
    }
    lsum += __shfl_xor(lsum, 1); lsq += __shfl_xor(lsq, 1);
    lsum += __shfl_xor(lsum, 2); lsq += __shfl_xor(lsq, 2);
    if (grp == 0) {
        int jg = jh*64 + jl;
        atomicAdd(&s2[jg], lsum);
        atomicAdd(&s2[CMM + jg], lsq);
    }
}

// ---------------------------------------------------------------------------
// k_mlp2: h = bn2(h0); mlp = h @ W2 + b2; out0 = pos + mlp[:,:2];
//         out1 = x + mlp[:,2:]
// grid = 256 (was 128): 32 n per block, 2 lanes per n (half = lane>>5),
// 16 j per thread, 8-way LDS reduce. Doubles CU coverage of a 1-wave/SIMD
// latency-bound kernel; red[] padded to 35 to break the 4-way bank alias.
// ---------------------------------------------------------------------------
__global__ __launch_bounds__(256) void k_mlp2(const float* __restrict__ h0,
                                              const float* __restrict__ x,
                                              const float* __restrict__ pos,
                                              const float* __restrict__ g2,
                                              const float* __restrict__ bt2,
                                              const float* __restrict__ W2,
                                              const float* __restrict__ b2,
                                              const float* __restrict__ s2,
                                              float* __restrict__ out) {
    __shared__ float red[8][32][35];   // 35 KB
    int t = threadIdx.x;
    int lane = t & 63, w = t >> 6;
    int half = lane >> 5;
    int nl = lane & 31;
    int n = blockIdx.x*32 + nl;
    int j0 = w*32 + half*16;
    float hv[16];
    #pragma unroll
    for (int q = 0; q < 4; ++q)
        *(float4*)&hv[q*4] = *(const float4*)&h0[(size_t)n*CMM + j0 + q*4];
    #pragma unroll
    for (int jj = 0; jj < 16; ++jj) {
        int j = j0 + jj;
        float mu  = s2[j] * (1.f/NTOT);
        float var = s2[CMM+j]*(1.f/NTOT) - mu*mu;
        float a   = g2[j] * rsqrtf(var + EPS);
        hv[jj] = a*(hv[jj] - mu) + bt2[j];
    }
    float acc[34];
    #pragma unroll
    for (int c = 0; c < 34; ++c) acc[c] = 0.f;
    for (int jj = 0; jj < 16; ++jj) {
        float h = hv[jj];
        const float* w2r = W2 + (size_t)(j0 + jj)*34;   // 2 addrs/wave -> broadcast
        #pragma unroll
        for (int c = 0; c < 34; ++c)
            acc[c] = fmaf(h, w2r[c], acc[c]);
    }
    int rid = w*2 + half;   // 0..7
    #pragma unroll
    for (int c = 0; c < 34; ++c) red[rid][nl][c] = acc[c];
    __syncthreads();
    // 32 n x 34 c = 1088 outputs over 256 threads
    for (int u = t; u < 32*34; u += 256) {
        int r = u / 34, c = u - r*34;
        float v = red[0][r][c] + red[1][r][c] + red[2][r][c] + red[3][r][c]
                + red[4][r][c] + red[5][r][c] + red[6][r][c] + red[7][r][c] + b2[c];
        int nn = blockIdx.x*32 + r;
        if (c < 2)
            out[(size_t)nn*2 + c] = pos[(size_t)nn*2 + c] + v;
        else
            out[16384 + (size_t)nn*32 + (c-2)] = x[(size_t)nn*32 + (c-2)] + v;
    }
}

// ---------------------------------------------------------------------------
extern "C" void kernel_launch(void* const* d_in, const int* in_sizes, int n_in,
                              void* d_out, int out_size, void* d_ws, size_t ws_size,
                              hipStream_t stream) {
    const float* positions = (const float*)d_in[0];
    const float* weights   = (const float*)d_in[1];
    // d_in[2] = batch (int32) — unused, shapes static
    const float* kpos = (const float*)d_in[3];
    const float* kw   = (const float*)d_in[4];
    const float* cg   = (const float*)d_in[5];
    const float* cb   = (const float*)d_in[6];
    const float* W1   = (const float*)d_in[7];
    const float* b1   = (const float*)d_in[8];
    const float* bg   = (const float*)d_in[9];
    const float* bb   = (const float*)d_in[10];
    const float* W2   = (const float*)d_in[11];
    const float* b2   = (const float*)d_in[12];
    float* ws  = (float*)d_ws;
    float* out = (float*)d_out;

    float* s1 = ws + OFF_ST;        // 64 floats
    float* s2 = ws + OFF_ST + 64;   // 256 floats

    k_convw<<<128, 256, 0, stream>>>(positions, kpos, weights, kw,
                                     ws + OFF_CFX, ws + OFF_CFY, ws + OFF_CF0,
                                     s1, (short*)(ws + OFF_CWT));
    k_sample<<<1024, 256, 0, stream>>>(positions, ws + OFF_CFX, ws + OFF_CFY,
                                       ws + OFF_CF0, (const short*)(ws + OFF_CWT),
                                       ws + OFF_PART);
    k_leaky_stats<<<256, 256, 0, stream>>>(ws + OFF_PART, ws + OFF_X0, s1);
    k_mlp1<<<256, 256, 0, stream>>>(ws + OFF_X0, weights, cg, cb, W1, b1,
                                    s1, ws + OFF_X, ws + OFF_H0, s2);
    k_mlp2<<<256, 256, 0, stream>>>(ws + OFF_H0, ws + OFF_X, positions,
                                    bg, bb, W2, b2, s2, out);
}